// Round 3
// baseline (711.446 us; speedup 1.0000x reference)
//
#include <hip/hip_runtime.h>
#include <math.h>

constexpr int NN = 100000;   // nodes
constexpr int NE = 1600000;  // edges
constexpr int DI = 128;      // input dim
constexpr int DH = 128;      // hidden dim
constexpr int NC = 64;       // classes
constexpr int NB = (NN + 255) / 256;   // 391 scan blocks

// ---------------------------------------------------------------------------
// Kernel 1: z1 = l2normalize(x) @ W1 + b1
// 4 rows per wave per iteration: each sW read feeds 8 FMAs (was 1).
// 1024 grid-stride blocks so W1 staging (64KB) is paid 1024x, not 6250x.
// ---------------------------------------------------------------------------
__global__ __launch_bounds__(256) void k_norm_gemm1(
    const float* __restrict__ x, const float* __restrict__ W1,
    const float* __restrict__ b1, float* __restrict__ z1)
{
    __shared__ float sW[DI * DH];    // 64 KB
    __shared__ float sx[4][4][DI];   // wave x row x dim, 8 KB

    const int tid = threadIdx.x;
    const float4* W4 = (const float4*)W1;
    float4* sW4 = (float4*)sW;
    #pragma unroll
    for (int i = 0; i < DI * DH / 4 / 256; ++i)
        sW4[tid + i * 256] = W4[tid + i * 256];
    __syncthreads();

    const int wave = tid >> 6, lane = tid & 63;
    const float bias0 = b1[lane];
    const float bias1 = b1[64 + lane];

    for (int base = (blockIdx.x * 4 + wave) * 4; base < NN;
         base += gridDim.x * 16) {
        // normalize 4 rows into per-wave LDS
        #pragma unroll
        for (int r = 0; r < 4; ++r) {
            const int row = base + r;
            float a0 = 0.f, a1 = 0.f;
            if (row < NN) {
                a0 = x[(size_t)row * DI + lane];
                a1 = x[(size_t)row * DI + 64 + lane];
            }
            float ss = a0 * a0 + a1 * a1;
            #pragma unroll
            for (int off = 32; off; off >>= 1) ss += __shfl_xor(ss, off);
            const float rinv = 1.0f / fmaxf(sqrtf(ss), 1e-12f);
            sx[wave][r][lane]      = a0 * rinv;
            sx[wave][r][64 + lane] = a1 * rinv;
        }
        float acc[4][2];
        #pragma unroll
        for (int r = 0; r < 4; ++r) { acc[r][0] = bias0; acc[r][1] = bias1; }

        #pragma unroll
        for (int k = 0; k < DI; k += 4) {
            float xv[4][4];
            #pragma unroll
            for (int r = 0; r < 4; ++r)
                *(float4*)xv[r] = *(const float4*)(&sx[wave][r][k]);
            #pragma unroll
            for (int j = 0; j < 4; ++j) {
                const float w0 = sW[(k + j) * DH + lane];
                const float w1 = sW[(k + j) * DH + 64 + lane];
                #pragma unroll
                for (int r = 0; r < 4; ++r) {
                    acc[r][0] = fmaf(xv[r][j], w0, acc[r][0]);
                    acc[r][1] = fmaf(xv[r][j], w1, acc[r][1]);
                }
            }
        }
        #pragma unroll
        for (int r = 0; r < 4; ++r) {
            const int row = base + r;
            if (row < NN) {
                z1[(size_t)row * DH + lane]      = acc[r][0];
                z1[(size_t)row * DH + 64 + lane] = acc[r][1];
            }
        }
    }
}

// ---------------------------------------------------------------------------
// CSR build: histogram -> 3-kernel exclusive scan -> (src,w) scatter
// ---------------------------------------------------------------------------
__global__ __launch_bounds__(256) void k_hist(
    const int* __restrict__ dst, int* __restrict__ cnt)
{
    for (int e = blockIdx.x * 256 + threadIdx.x; e < NE; e += gridDim.x * 256)
        atomicAdd(&cnt[dst[e]], 1);
}

__global__ __launch_bounds__(256) void k_scanA(
    const int* __restrict__ cnt, int* __restrict__ rowptr,
    int* __restrict__ bsum)
{
    __shared__ int tmp[256];
    const int t = threadIdx.x;
    const int gid = blockIdx.x * 256 + t;
    const int v = (gid < NN) ? cnt[gid] : 0;
    tmp[t] = v;
    __syncthreads();
    #pragma unroll
    for (int off = 1; off < 256; off <<= 1) {
        const int add = (t >= off) ? tmp[t - off] : 0;
        __syncthreads();
        tmp[t] += add;
        __syncthreads();
    }
    if (gid < NN) rowptr[gid] = tmp[t] - v;
    if (t == 255) bsum[blockIdx.x] = tmp[255];
}

__global__ __launch_bounds__(512) void k_scanB(int* __restrict__ bsum)
{
    __shared__ int tmp[512];
    const int t = threadIdx.x;
    const int v = (t < NB) ? bsum[t] : 0;
    tmp[t] = v;
    __syncthreads();
    #pragma unroll
    for (int off = 1; off < 512; off <<= 1) {
        const int add = (t >= off) ? tmp[t - off] : 0;
        __syncthreads();
        tmp[t] += add;
        __syncthreads();
    }
    if (t < NB) bsum[t] = tmp[t] - v;
}

__global__ __launch_bounds__(256) void k_scanC(
    int* __restrict__ rowptr, const int* __restrict__ bsum,
    int* __restrict__ offs)
{
    const int gid = blockIdx.x * 256 + threadIdx.x;
    if (gid < NN) {
        const int r = rowptr[gid] + bsum[blockIdx.x];
        rowptr[gid] = r;
        offs[gid]   = r;
    }
    if (gid == 0) rowptr[NN] = NE;
}

__global__ __launch_bounds__(256) void k_scatter(
    const int* __restrict__ src, const int* __restrict__ dst,
    const float* __restrict__ ew, int* __restrict__ offs,
    int2* __restrict__ srcw)
{
    for (int e = blockIdx.x * 256 + threadIdx.x; e < NE; e += gridDim.x * 256) {
        const int pos = atomicAdd(&offs[dst[e]], 1);
        srcw[pos] = make_int2(src[e], __float_as_int(ew[e]));
    }
}

// ---------------------------------------------------------------------------
// Fused: agg = relu(spmm(h)); z2 = agg @ W2 + b2 -- agg never leaves LDS.
// One wave per row, grid-stride (W2 staged once per block). Gather x4 unroll.
// ---------------------------------------------------------------------------
__global__ __launch_bounds__(256) void k_spmm1_gemm2(
    const float* __restrict__ h, const int* __restrict__ rowptr,
    const int2* __restrict__ srcw, const float* __restrict__ W2,
    const float* __restrict__ b2, float* __restrict__ z2)
{
    __shared__ float sW2[DH * NC];   // 32 KB
    __shared__ float sagg[4][DH];    // 2 KB

    const int tid = threadIdx.x;
    {
        const float4* W4 = (const float4*)W2;
        float4* s4 = (float4*)sW2;
        #pragma unroll
        for (int i = 0; i < DH * NC / 4 / 256; ++i)
            s4[tid + i * 256] = W4[tid + i * 256];
    }
    __syncthreads();

    const int wave = tid >> 6, lane = tid & 63;
    const float bias = b2[lane];

    for (int row = blockIdx.x * 4 + wave; row < NN; row += gridDim.x * 4) {
        const int start = rowptr[row], end = rowptr[row + 1];
        float acc0 = 0.f, acc1 = 0.f;
        int e = start;
        for (; e + 4 <= end; e += 4) {
            const int2 s0 = srcw[e + 0], s1 = srcw[e + 1];
            const int2 s2 = srcw[e + 2], s3 = srcw[e + 3];
            const float* p0 = h + (size_t)s0.x * DH;
            const float* p1 = h + (size_t)s1.x * DH;
            const float* p2 = h + (size_t)s2.x * DH;
            const float* p3 = h + (size_t)s3.x * DH;
            const float v00 = p0[lane], v01 = p0[64 + lane];
            const float v10 = p1[lane], v11 = p1[64 + lane];
            const float v20 = p2[lane], v21 = p2[64 + lane];
            const float v30 = p3[lane], v31 = p3[64 + lane];
            acc0 = fmaf(__int_as_float(s0.y), v00, acc0);
            acc1 = fmaf(__int_as_float(s0.y), v01, acc1);
            acc0 = fmaf(__int_as_float(s1.y), v10, acc0);
            acc1 = fmaf(__int_as_float(s1.y), v11, acc1);
            acc0 = fmaf(__int_as_float(s2.y), v20, acc0);
            acc1 = fmaf(__int_as_float(s2.y), v21, acc1);
            acc0 = fmaf(__int_as_float(s3.y), v30, acc0);
            acc1 = fmaf(__int_as_float(s3.y), v31, acc1);
        }
        for (; e < end; ++e) {
            const int2 s = srcw[e];
            const float* p = h + (size_t)s.x * DH;
            acc0 = fmaf(__int_as_float(s.y), p[lane],      acc0);
            acc1 = fmaf(__int_as_float(s.y), p[64 + lane], acc1);
        }
        // ReLU into per-wave LDS, then 128x64 GEMM (agg never hits global)
        sagg[wave][lane]      = fmaxf(acc0, 0.f);
        sagg[wave][64 + lane] = fmaxf(acc1, 0.f);

        float acc = bias;
        #pragma unroll
        for (int k = 0; k < DH; k += 4) {
            float a4[4];
            *(float4*)a4 = *(const float4*)(&sagg[wave][k]);
            acc = fmaf(a4[0], sW2[(k + 0) * NC + lane], acc);
            acc = fmaf(a4[1], sW2[(k + 1) * NC + lane], acc);
            acc = fmaf(a4[2], sW2[(k + 2) * NC + lane], acc);
            acc = fmaf(a4[3], sW2[(k + 3) * NC + lane], acc);
        }
        z2[(size_t)row * NC + lane] = acc;
    }
}

// ---------------------------------------------------------------------------
// Gather-SPMM D=64 + fused softmax, x4 edge unroll
// ---------------------------------------------------------------------------
__global__ __launch_bounds__(256) void k_spmm2_softmax(
    const float* __restrict__ z2, const int* __restrict__ rowptr,
    const int2* __restrict__ srcw, float* __restrict__ out)
{
    const int row = blockIdx.x * 4 + (threadIdx.x >> 6);
    if (row >= NN) return;
    const int lane = threadIdx.x & 63;
    const int start = rowptr[row], end = rowptr[row + 1];
    float acc = 0.f;
    int e = start;
    for (; e + 4 <= end; e += 4) {
        const int2 s0 = srcw[e + 0], s1 = srcw[e + 1];
        const int2 s2 = srcw[e + 2], s3 = srcw[e + 3];
        const float v0 = z2[(size_t)s0.x * NC + lane];
        const float v1 = z2[(size_t)s1.x * NC + lane];
        const float v2 = z2[(size_t)s2.x * NC + lane];
        const float v3 = z2[(size_t)s3.x * NC + lane];
        acc = fmaf(__int_as_float(s0.y), v0, acc);
        acc = fmaf(__int_as_float(s1.y), v1, acc);
        acc = fmaf(__int_as_float(s2.y), v2, acc);
        acc = fmaf(__int_as_float(s3.y), v3, acc);
    }
    for (; e < end; ++e) {
        const int2 s = srcw[e];
        acc = fmaf(__int_as_float(s.y), z2[(size_t)s.x * NC + lane], acc);
    }
    float m = acc;
    #pragma unroll
    for (int off = 32; off; off >>= 1) m = fmaxf(m, __shfl_xor(m, off));
    const float ex = __expf(acc - m);
    float s = ex;
    #pragma unroll
    for (int off = 32; off; off >>= 1) s += __shfl_xor(s, off);
    out[(size_t)row * NC + lane] = ex / s;
}

// ---------------------------------------------------------------------------
extern "C" void kernel_launch(void* const* d_in, const int* in_sizes, int n_in,
                              void* d_out, int out_size, void* d_ws,
                              size_t ws_size, hipStream_t stream)
{
    const float* x  = (const float*)d_in[0];
    const int* src  = (const int*)d_in[1];
    const int* dst  = (const int*)d_in[2];
    const float* ew = (const float*)d_in[3];
    const float* W1 = (const float*)d_in[4];
    const float* b1 = (const float*)d_in[5];
    const float* W2 = (const float*)d_in[6];
    const float* b2 = (const float*)d_in[7];
    float* out = (float*)d_out;

    // workspace layout:
    //   z1   [NN*DH*4] = 51.2 MB
    //   z2   [NN*NC*4] = 25.6 MB
    //   srcw [NE*8]    = 12.8 MB
    //   rowptr [(NN+2)*4], offs/cnt [NN*4], bsum [512*4]
    char* base = (char*)d_ws;
    float* z1   = (float*)base;                 base += (size_t)NN * DH * 4;
    float* z2   = (float*)base;                 base += (size_t)NN * NC * 4;
    int2*  srcw = (int2*)base;                  base += (size_t)NE * 8;
    int* rowptr = (int*)base;                   base += ((size_t)NN + 2) * 4;
    int* offs   = (int*)base;                   base += (size_t)NN * 4;
    int* bsum   = (int*)base;                   base += 512 * 4;
    int* cnt    = offs;                         // cnt dead after scanA

    hipMemsetAsync(cnt, 0, (size_t)NN * 4, stream);

    k_norm_gemm1<<<1024, 256, 0, stream>>>(x, W1, b1, z1);

    k_hist   <<<2048, 256, 0, stream>>>(dst, cnt);
    k_scanA  <<<NB, 256, 0, stream>>>(cnt, rowptr, bsum);
    k_scanB  <<<1, 512, 0, stream>>>(bsum);
    k_scanC  <<<NB, 256, 0, stream>>>(rowptr, bsum, offs);
    k_scatter<<<2048, 256, 0, stream>>>(src, dst, ew, offs, srcw);

    k_spmm1_gemm2   <<<2048, 256, 0, stream>>>(z1, rowptr, srcw, W2, b2, z2);
    k_spmm2_softmax <<<(NN + 3) / 4, 256, 0, stream>>>(z2, rowptr, srcw, out);
}

// Round 4
// 627.491 us; speedup vs baseline: 1.1338x; 1.1338x over previous
//
#include <hip/hip_runtime.h>
#include <math.h>

constexpr int NN = 100000;   // nodes
constexpr int NE = 1600000;  // edges
constexpr int DI = 128;      // input dim
constexpr int DH = 128;      // hidden dim
constexpr int NC = 64;       // classes
constexpr int NB = (NN + 255) / 256;   // 391 scan blocks

// ---------------------------------------------------------------------------
// Kernel 1: z1 = l2normalize(x) @ W1 + b1
// 2 rows per wave; W1 staged PAIRED in LDS: sW[k*128 + 2c] = W1[k][c],
// sW[k*128 + 2c+1] = W1[k][c+64]  ->  one ds_read_b64 per (k, lane) feeds
// 4 FMAs. VGPR kept low on purpose (round-3 4-row variant spilled at 256).
// ---------------------------------------------------------------------------
__global__ __launch_bounds__(256) void k_norm_gemm1(
    const float* __restrict__ x, const float* __restrict__ W1,
    const float* __restrict__ b1, float* __restrict__ z1)
{
    __shared__ float sW[DI * DH];    // 64 KB, paired layout
    __shared__ float sx[4][2][DI];   // wave x row x dim, 4 KB

    const int tid = threadIdx.x;
    // paired staging: thread handles (k, c): reads W1[k][c], W1[k][c+64]
    for (int i = tid; i < DI * 64; i += 256) {
        const int k = i >> 6, c = i & 63;
        const float2 p = make_float2(W1[(size_t)k * DH + c],
                                     W1[(size_t)k * DH + c + 64]);
        *(float2*)&sW[(size_t)k * DH + 2 * c] = p;
    }
    __syncthreads();

    const int wave = tid >> 6, lane = tid & 63;
    const float bias0 = b1[lane];
    const float bias1 = b1[64 + lane];

    for (int base = (blockIdx.x * 4 + wave) * 2; base < NN;
         base += gridDim.x * 8) {
        // normalize 2 rows into per-wave LDS
        #pragma unroll
        for (int r = 0; r < 2; ++r) {
            const int row = base + r;
            float a0 = 0.f, a1 = 0.f;
            if (row < NN) {
                a0 = x[(size_t)row * DI + lane];
                a1 = x[(size_t)row * DI + 64 + lane];
            }
            float ss = a0 * a0 + a1 * a1;
            #pragma unroll
            for (int off = 32; off; off >>= 1) ss += __shfl_xor(ss, off);
            const float rinv = 1.0f / fmaxf(sqrtf(ss), 1e-12f);
            sx[wave][r][lane]      = a0 * rinv;
            sx[wave][r][64 + lane] = a1 * rinv;
        }

        float acc00 = bias0, acc01 = bias1;   // row 0
        float acc10 = bias0, acc11 = bias1;   // row 1

        #pragma unroll
        for (int k = 0; k < DI; k += 4) {
            float xa[4], xb[4];
            *(float4*)xa = *(const float4*)(&sx[wave][0][k]);
            *(float4*)xb = *(const float4*)(&sx[wave][1][k]);
            #pragma unroll
            for (int j = 0; j < 4; ++j) {
                const float2 w = *(const float2*)(&sW[(k + j) * DH + 2 * lane]);
                acc00 = fmaf(xa[j], w.x, acc00);
                acc01 = fmaf(xa[j], w.y, acc01);
                acc10 = fmaf(xb[j], w.x, acc10);
                acc11 = fmaf(xb[j], w.y, acc11);
            }
        }
        if (base < NN) {
            z1[(size_t)base * DH + lane]      = acc00;
            z1[(size_t)base * DH + 64 + lane] = acc01;
        }
        if (base + 1 < NN) {
            z1[(size_t)(base + 1) * DH + lane]      = acc10;
            z1[(size_t)(base + 1) * DH + 64 + lane] = acc11;
        }
    }
}

// ---------------------------------------------------------------------------
// CSR build: histogram -> 3-kernel exclusive scan -> (src,w) scatter
// ---------------------------------------------------------------------------
__global__ __launch_bounds__(256) void k_hist(
    const int* __restrict__ dst, int* __restrict__ cnt)
{
    for (int e = blockIdx.x * 256 + threadIdx.x; e < NE; e += gridDim.x * 256)
        atomicAdd(&cnt[dst[e]], 1);
}

__global__ __launch_bounds__(256) void k_scanA(
    const int* __restrict__ cnt, int* __restrict__ rowptr,
    int* __restrict__ bsum)
{
    __shared__ int tmp[256];
    const int t = threadIdx.x;
    const int gid = blockIdx.x * 256 + t;
    const int v = (gid < NN) ? cnt[gid] : 0;
    tmp[t] = v;
    __syncthreads();
    #pragma unroll
    for (int off = 1; off < 256; off <<= 1) {
        const int add = (t >= off) ? tmp[t - off] : 0;
        __syncthreads();
        tmp[t] += add;
        __syncthreads();
    }
    if (gid < NN) rowptr[gid] = tmp[t] - v;
    if (t == 255) bsum[blockIdx.x] = tmp[255];
}

__global__ __launch_bounds__(512) void k_scanB(int* __restrict__ bsum)
{
    __shared__ int tmp[512];
    const int t = threadIdx.x;
    const int v = (t < NB) ? bsum[t] : 0;
    tmp[t] = v;
    __syncthreads();
    #pragma unroll
    for (int off = 1; off < 512; off <<= 1) {
        const int add = (t >= off) ? tmp[t - off] : 0;
        __syncthreads();
        tmp[t] += add;
        __syncthreads();
    }
    if (t < NB) bsum[t] = tmp[t] - v;
}

__global__ __launch_bounds__(256) void k_scanC(
    int* __restrict__ rowptr, const int* __restrict__ bsum,
    int* __restrict__ offs)
{
    const int gid = blockIdx.x * 256 + threadIdx.x;
    if (gid < NN) {
        const int r = rowptr[gid] + bsum[blockIdx.x];
        rowptr[gid] = r;
        offs[gid]   = r;
    }
    if (gid == 0) rowptr[NN] = NE;
}

__global__ __launch_bounds__(256) void k_scatter(
    const int* __restrict__ src, const int* __restrict__ dst,
    const float* __restrict__ ew, int* __restrict__ offs,
    int2* __restrict__ srcw)
{
    for (int e = blockIdx.x * 256 + threadIdx.x; e < NE; e += gridDim.x * 256) {
        const int pos = atomicAdd(&offs[dst[e]], 1);
        srcw[pos] = make_int2(src[e], __float_as_int(ew[e]));
    }
}

// ---------------------------------------------------------------------------
// Fused: agg = relu(spmm(h)); z2 = agg @ W2 + b2 -- agg never leaves LDS.
// One wave per row, grid-stride (W2 staged once per block). Gather x4 unroll.
// ---------------------------------------------------------------------------
__global__ __launch_bounds__(256) void k_spmm1_gemm2(
    const float* __restrict__ h, const int* __restrict__ rowptr,
    const int2* __restrict__ srcw, const float* __restrict__ W2,
    const float* __restrict__ b2, float* __restrict__ z2)
{
    __shared__ float sW2[DH * NC];   // 32 KB
    __shared__ float sagg[4][DH];    // 2 KB

    const int tid = threadIdx.x;
    {
        const float4* W4 = (const float4*)W2;
        float4* s4 = (float4*)sW2;
        #pragma unroll
        for (int i = 0; i < DH * NC / 4 / 256; ++i)
            s4[tid + i * 256] = W4[tid + i * 256];
    }
    __syncthreads();

    const int wave = tid >> 6, lane = tid & 63;
    const float bias = b2[lane];

    for (int row = blockIdx.x * 4 + wave; row < NN; row += gridDim.x * 4) {
        const int start = rowptr[row], end = rowptr[row + 1];
        float acc0 = 0.f, acc1 = 0.f;
        int e = start;
        for (; e + 4 <= end; e += 4) {
            const int2 s0 = srcw[e + 0], s1 = srcw[e + 1];
            const int2 s2 = srcw[e + 2], s3 = srcw[e + 3];
            const float* p0 = h + (size_t)s0.x * DH;
            const float* p1 = h + (size_t)s1.x * DH;
            const float* p2 = h + (size_t)s2.x * DH;
            const float* p3 = h + (size_t)s3.x * DH;
            const float v00 = p0[lane], v01 = p0[64 + lane];
            const float v10 = p1[lane], v11 = p1[64 + lane];
            const float v20 = p2[lane], v21 = p2[64 + lane];
            const float v30 = p3[lane], v31 = p3[64 + lane];
            acc0 = fmaf(__int_as_float(s0.y), v00, acc0);
            acc1 = fmaf(__int_as_float(s0.y), v01, acc1);
            acc0 = fmaf(__int_as_float(s1.y), v10, acc0);
            acc1 = fmaf(__int_as_float(s1.y), v11, acc1);
            acc0 = fmaf(__int_as_float(s2.y), v20, acc0);
            acc1 = fmaf(__int_as_float(s2.y), v21, acc1);
            acc0 = fmaf(__int_as_float(s3.y), v30, acc0);
            acc1 = fmaf(__int_as_float(s3.y), v31, acc1);
        }
        for (; e < end; ++e) {
            const int2 s = srcw[e];
            const float* p = h + (size_t)s.x * DH;
            acc0 = fmaf(__int_as_float(s.y), p[lane],      acc0);
            acc1 = fmaf(__int_as_float(s.y), p[64 + lane], acc1);
        }
        // ReLU into per-wave LDS, then 128x64 GEMM (agg never hits global)
        sagg[wave][lane]      = fmaxf(acc0, 0.f);
        sagg[wave][64 + lane] = fmaxf(acc1, 0.f);

        float acc = bias;
        #pragma unroll
        for (int k = 0; k < DH; k += 4) {
            float a4[4];
            *(float4*)a4 = *(const float4*)(&sagg[wave][k]);
            acc = fmaf(a4[0], sW2[(k + 0) * NC + lane], acc);
            acc = fmaf(a4[1], sW2[(k + 1) * NC + lane], acc);
            acc = fmaf(a4[2], sW2[(k + 2) * NC + lane], acc);
            acc = fmaf(a4[3], sW2[(k + 3) * NC + lane], acc);
        }
        z2[(size_t)row * NC + lane] = acc;
    }
}

// ---------------------------------------------------------------------------
// Gather-SPMM D=64 + fused softmax, x4 edge unroll
// ---------------------------------------------------------------------------
__global__ __launch_bounds__(256) void k_spmm2_softmax(
    const float* __restrict__ z2, const int* __restrict__ rowptr,
    const int2* __restrict__ srcw, float* __restrict__ out)
{
    const int row = blockIdx.x * 4 + (threadIdx.x >> 6);
    if (row >= NN) return;
    const int lane = threadIdx.x & 63;
    const int start = rowptr[row], end = rowptr[row + 1];
    float acc = 0.f;
    int e = start;
    for (; e + 4 <= end; e += 4) {
        const int2 s0 = srcw[e + 0], s1 = srcw[e + 1];
        const int2 s2 = srcw[e + 2], s3 = srcw[e + 3];
        const float v0 = z2[(size_t)s0.x * NC + lane];
        const float v1 = z2[(size_t)s1.x * NC + lane];
        const float v2 = z2[(size_t)s2.x * NC + lane];
        const float v3 = z2[(size_t)s3.x * NC + lane];
        acc = fmaf(__int_as_float(s0.y), v0, acc);
        acc = fmaf(__int_as_float(s1.y), v1, acc);
        acc = fmaf(__int_as_float(s2.y), v2, acc);
        acc = fmaf(__int_as_float(s3.y), v3, acc);
    }
    for (; e < end; ++e) {
        const int2 s = srcw[e];
        acc = fmaf(__int_as_float(s.y), z2[(size_t)s.x * NC + lane], acc);
    }
    float m = acc;
    #pragma unroll
    for (int off = 32; off; off >>= 1) m = fmaxf(m, __shfl_xor(m, off));
    const float ex = __expf(acc - m);
    float s = ex;
    #pragma unroll
    for (int off = 32; off; off >>= 1) s += __shfl_xor(s, off);
    out[(size_t)row * NC + lane] = ex / s;
}

// ---------------------------------------------------------------------------
extern "C" void kernel_launch(void* const* d_in, const int* in_sizes, int n_in,
                              void* d_out, int out_size, void* d_ws,
                              size_t ws_size, hipStream_t stream)
{
    const float* x  = (const float*)d_in[0];
    const int* src  = (const int*)d_in[1];
    const int* dst  = (const int*)d_in[2];
    const float* ew = (const float*)d_in[3];
    const float* W1 = (const float*)d_in[4];
    const float* b1 = (const float*)d_in[5];
    const float* W2 = (const float*)d_in[6];
    const float* b2 = (const float*)d_in[7];
    float* out = (float*)d_out;

    // workspace layout:
    //   z1   [NN*DH*4] = 51.2 MB
    //   z2   [NN*NC*4] = 25.6 MB
    //   srcw [NE*8]    = 12.8 MB
    //   rowptr [(NN+2)*4], offs/cnt [NN*4], bsum [512*4]
    char* base = (char*)d_ws;
    float* z1   = (float*)base;                 base += (size_t)NN * DH * 4;
    float* z2   = (float*)base;                 base += (size_t)NN * NC * 4;
    int2*  srcw = (int2*)base;                  base += (size_t)NE * 8;
    int* rowptr = (int*)base;                   base += ((size_t)NN + 2) * 4;
    int* offs   = (int*)base;                   base += (size_t)NN * 4;
    int* bsum   = (int*)base;                   base += 512 * 4;
    int* cnt    = offs;                         // cnt dead after scanA

    hipMemsetAsync(cnt, 0, (size_t)NN * 4, stream);

    k_norm_gemm1<<<1024, 256, 0, stream>>>(x, W1, b1, z1);

    k_hist   <<<2048, 256, 0, stream>>>(dst, cnt);
    k_scanA  <<<NB, 256, 0, stream>>>(cnt, rowptr, bsum);
    k_scanB  <<<1, 512, 0, stream>>>(bsum);
    k_scanC  <<<NB, 256, 0, stream>>>(rowptr, bsum, offs);
    k_scatter<<<2048, 256, 0, stream>>>(src, dst, ew, offs, srcw);

    k_spmm1_gemm2   <<<2048, 256, 0, stream>>>(z1, rowptr, srcw, W2, b2, z2);
    k_spmm2_softmax <<<(NN + 3) / 4, 256, 0, stream>>>(z2, rowptr, srcw, out);
}

// Round 5
// 484.598 us; speedup vs baseline: 1.4681x; 1.2949x over previous
//
#include <hip/hip_runtime.h>
#include <math.h>

constexpr int NN = 100000;   // nodes
constexpr int NE = 1600000;  // edges
constexpr int DI = 128;      // input dim
constexpr int DH = 128;      // hidden dim
constexpr int NC = 64;       // classes
constexpr int NB = (NN + 255) / 256;   // 391 scan blocks

// ---------------------------------------------------------------------------
// Kernel 1: z1 = l2normalize(x) @ W1 + b1
// 512 threads (8 waves), 4 rows/wave/iter. W staged quad-paired:
//   sW4[k/2][c] = {W[k][c], W[k][c+64], W[k+1][c], W[k+1][c+64]}
// -> one sequential conflict-free ds_read_b128 per 2 k-values (the round-4
// paired-b64 layout was a 4-way bank conflict, 524K conflicts measured).
// LDS 80KB -> exactly 2 blocks/CU = 16 waves/CU (was 8). W LDS traffic
// halves (16KB/row). #pragma unroll 2 keeps VGPR bounded (round-3 lesson).
// ---------------------------------------------------------------------------
__global__ __launch_bounds__(512) void k_norm_gemm1(
    const float* __restrict__ x, const float* __restrict__ W1,
    const float* __restrict__ b1, float* __restrict__ z1)
{
    __shared__ float4 sW4[64][64];   // 64 KB quad-paired
    __shared__ float sx[8][4][DI];   // 16 KB: wave x row x k

    const int tid = threadIdx.x;
    for (int i = tid; i < 64 * 64; i += 512) {
        const int k2 = i >> 6, c = i & 63;
        const float* wp = W1 + (size_t)(2 * k2) * DH + c;
        sW4[k2][c] = make_float4(wp[0], wp[64], wp[DH], wp[DH + 64]);
    }
    __syncthreads();

    const int wave = tid >> 6, lane = tid & 63;
    const float bias0 = b1[lane];
    const float bias1 = b1[64 + lane];

    for (int base = (blockIdx.x * 8 + wave) * 4; base < NN;
         base += gridDim.x * 32) {
        // normalize 4 rows into per-wave LDS (writes: 2 lanes/bank = free)
        #pragma unroll
        for (int r = 0; r < 4; ++r) {
            const int row = base + r;
            float a0 = 0.f, a1 = 0.f;
            if (row < NN) {
                a0 = x[(size_t)row * DI + lane];
                a1 = x[(size_t)row * DI + 64 + lane];
            }
            float ss = a0 * a0 + a1 * a1;
            #pragma unroll
            for (int off = 32; off; off >>= 1) ss += __shfl_xor(ss, off);
            const float rinv = 1.0f / fmaxf(sqrtf(ss), 1e-12f);
            sx[wave][r][lane]      = a0 * rinv;
            sx[wave][r][64 + lane] = a1 * rinv;
        }

        float acc[4][2];
        #pragma unroll
        for (int r = 0; r < 4; ++r) { acc[r][0] = bias0; acc[r][1] = bias1; }

        #pragma unroll 2
        for (int k2 = 0; k2 < 64; k2 += 2) {   // 4 k-values per iter
            const float4 w0 = sW4[k2][lane];       // seq b128, conflict-free
            const float4 w1 = sW4[k2 + 1][lane];
            #pragma unroll
            for (int r = 0; r < 4; ++r) {
                const float4 xv = *(const float4*)(&sx[wave][r][2 * k2]); // broadcast
                acc[r][0] = fmaf(xv.x, w0.x, acc[r][0]);
                acc[r][1] = fmaf(xv.x, w0.y, acc[r][1]);
                acc[r][0] = fmaf(xv.y, w0.z, acc[r][0]);
                acc[r][1] = fmaf(xv.y, w0.w, acc[r][1]);
                acc[r][0] = fmaf(xv.z, w1.x, acc[r][0]);
                acc[r][1] = fmaf(xv.z, w1.y, acc[r][1]);
                acc[r][0] = fmaf(xv.w, w1.z, acc[r][0]);
                acc[r][1] = fmaf(xv.w, w1.w, acc[r][1]);
            }
        }
        #pragma unroll
        for (int r = 0; r < 4; ++r) {
            const int row = base + r;
            if (row < NN) {
                z1[(size_t)row * DH + lane]      = acc[r][0];
                z1[(size_t)row * DH + 64 + lane] = acc[r][1];
            }
        }
    }
}

// ---------------------------------------------------------------------------
// CSR build: histogram -> 3-kernel exclusive scan -> (src,w) scatter
// ---------------------------------------------------------------------------
__global__ __launch_bounds__(256) void k_hist(
    const int* __restrict__ dst, int* __restrict__ cnt)
{
    for (int e = blockIdx.x * 256 + threadIdx.x; e < NE; e += gridDim.x * 256)
        atomicAdd(&cnt[dst[e]], 1);
}

__global__ __launch_bounds__(256) void k_scanA(
    const int* __restrict__ cnt, int* __restrict__ rowptr,
    int* __restrict__ bsum)
{
    __shared__ int tmp[256];
    const int t = threadIdx.x;
    const int gid = blockIdx.x * 256 + t;
    const int v = (gid < NN) ? cnt[gid] : 0;
    tmp[t] = v;
    __syncthreads();
    #pragma unroll
    for (int off = 1; off < 256; off <<= 1) {
        const int add = (t >= off) ? tmp[t - off] : 0;
        __syncthreads();
        tmp[t] += add;
        __syncthreads();
    }
    if (gid < NN) rowptr[gid] = tmp[t] - v;
    if (t == 255) bsum[blockIdx.x] = tmp[255];
}

__global__ __launch_bounds__(512) void k_scanB(int* __restrict__ bsum)
{
    __shared__ int tmp[512];
    const int t = threadIdx.x;
    const int v = (t < NB) ? bsum[t] : 0;
    tmp[t] = v;
    __syncthreads();
    #pragma unroll
    for (int off = 1; off < 512; off <<= 1) {
        const int add = (t >= off) ? tmp[t - off] : 0;
        __syncthreads();
        tmp[t] += add;
        __syncthreads();
    }
    if (t < NB) bsum[t] = tmp[t] - v;
}

__global__ __launch_bounds__(256) void k_scanC(
    int* __restrict__ rowptr, const int* __restrict__ bsum,
    int* __restrict__ offs)
{
    const int gid = blockIdx.x * 256 + threadIdx.x;
    if (gid < NN) {
        const int r = rowptr[gid] + bsum[blockIdx.x];
        rowptr[gid] = r;
        offs[gid]   = r;
    }
    if (gid == 0) rowptr[NN] = NE;
}

__global__ __launch_bounds__(256) void k_scatter(
    const int* __restrict__ src, const int* __restrict__ dst,
    const float* __restrict__ ew, int* __restrict__ offs,
    int2* __restrict__ srcw)
{
    for (int e = blockIdx.x * 256 + threadIdx.x; e < NE; e += gridDim.x * 256) {
        const int pos = atomicAdd(&offs[dst[e]], 1);
        srcw[pos] = make_int2(src[e], __float_as_int(ew[e]));
    }
}

// ---------------------------------------------------------------------------
// Fused: agg = relu(spmm(h)); z2 = agg @ W2 + b2 -- agg never leaves LDS.
// One wave per row, grid-stride (W2 staged once per block). Gather x4 unroll.
// ---------------------------------------------------------------------------
__global__ __launch_bounds__(256) void k_spmm1_gemm2(
    const float* __restrict__ h, const int* __restrict__ rowptr,
    const int2* __restrict__ srcw, const float* __restrict__ W2,
    const float* __restrict__ b2, float* __restrict__ z2)
{
    __shared__ float sW2[DH * NC];   // 32 KB
    __shared__ float sagg[4][DH];    // 2 KB

    const int tid = threadIdx.x;
    {
        const float4* W4 = (const float4*)W2;
        float4* s4 = (float4*)sW2;
        #pragma unroll
        for (int i = 0; i < DH * NC / 4 / 256; ++i)
            s4[tid + i * 256] = W4[tid + i * 256];
    }
    __syncthreads();

    const int wave = tid >> 6, lane = tid & 63;
    const float bias = b2[lane];

    for (int row = blockIdx.x * 4 + wave; row < NN; row += gridDim.x * 4) {
        const int start = rowptr[row], end = rowptr[row + 1];
        float acc0 = 0.f, acc1 = 0.f;
        int e = start;
        for (; e + 4 <= end; e += 4) {
            const int2 s0 = srcw[e + 0], s1 = srcw[e + 1];
            const int2 s2 = srcw[e + 2], s3 = srcw[e + 3];
            const float* p0 = h + (size_t)s0.x * DH;
            const float* p1 = h + (size_t)s1.x * DH;
            const float* p2 = h + (size_t)s2.x * DH;
            const float* p3 = h + (size_t)s3.x * DH;
            const float v00 = p0[lane], v01 = p0[64 + lane];
            const float v10 = p1[lane], v11 = p1[64 + lane];
            const float v20 = p2[lane], v21 = p2[64 + lane];
            const float v30 = p3[lane], v31 = p3[64 + lane];
            acc0 = fmaf(__int_as_float(s0.y), v00, acc0);
            acc1 = fmaf(__int_as_float(s0.y), v01, acc1);
            acc0 = fmaf(__int_as_float(s1.y), v10, acc0);
            acc1 = fmaf(__int_as_float(s1.y), v11, acc1);
            acc0 = fmaf(__int_as_float(s2.y), v20, acc0);
            acc1 = fmaf(__int_as_float(s2.y), v21, acc1);
            acc0 = fmaf(__int_as_float(s3.y), v30, acc0);
            acc1 = fmaf(__int_as_float(s3.y), v31, acc1);
        }
        for (; e < end; ++e) {
            const int2 s = srcw[e];
            const float* p = h + (size_t)s.x * DH;
            acc0 = fmaf(__int_as_float(s.y), p[lane],      acc0);
            acc1 = fmaf(__int_as_float(s.y), p[64 + lane], acc1);
        }
        // ReLU into per-wave LDS, then 128x64 GEMM (agg never hits global)
        sagg[wave][lane]      = fmaxf(acc0, 0.f);
        sagg[wave][64 + lane] = fmaxf(acc1, 0.f);

        float acc = bias;
        #pragma unroll
        for (int k = 0; k < DH; k += 4) {
            float a4[4];
            *(float4*)a4 = *(const float4*)(&sagg[wave][k]);
            acc = fmaf(a4[0], sW2[(k + 0) * NC + lane], acc);
            acc = fmaf(a4[1], sW2[(k + 1) * NC + lane], acc);
            acc = fmaf(a4[2], sW2[(k + 2) * NC + lane], acc);
            acc = fmaf(a4[3], sW2[(k + 3) * NC + lane], acc);
        }
        z2[(size_t)row * NC + lane] = acc;
    }
}

// ---------------------------------------------------------------------------
// Gather-SPMM D=64 + fused softmax, x4 edge unroll
// ---------------------------------------------------------------------------
__global__ __launch_bounds__(256) void k_spmm2_softmax(
    const float* __restrict__ z2, const int* __restrict__ rowptr,
    const int2* __restrict__ srcw, float* __restrict__ out)
{
    const int row = blockIdx.x * 4 + (threadIdx.x >> 6);
    if (row >= NN) return;
    const int lane = threadIdx.x & 63;
    const int start = rowptr[row], end = rowptr[row + 1];
    float acc = 0.f;
    int e = start;
    for (; e + 4 <= end; e += 4) {
        const int2 s0 = srcw[e + 0], s1 = srcw[e + 1];
        const int2 s2 = srcw[e + 2], s3 = srcw[e + 3];
        const float v0 = z2[(size_t)s0.x * NC + lane];
        const float v1 = z2[(size_t)s1.x * NC + lane];
        const float v2 = z2[(size_t)s2.x * NC + lane];
        const float v3 = z2[(size_t)s3.x * NC + lane];
        acc = fmaf(__int_as_float(s0.y), v0, acc);
        acc = fmaf(__int_as_float(s1.y), v1, acc);
        acc = fmaf(__int_as_float(s2.y), v2, acc);
        acc = fmaf(__int_as_float(s3.y), v3, acc);
    }
    for (; e < end; ++e) {
        const int2 s = srcw[e];
        acc = fmaf(__int_as_float(s.y), z2[(size_t)s.x * NC + lane], acc);
    }
    float m = acc;
    #pragma unroll
    for (int off = 32; off; off >>= 1) m = fmaxf(m, __shfl_xor(m, off));
    const float ex = __expf(acc - m);
    float s = ex;
    #pragma unroll
    for (int off = 32; off; off >>= 1) s += __shfl_xor(s, off);
    out[(size_t)row * NC + lane] = ex / s;
}

// ---------------------------------------------------------------------------
extern "C" void kernel_launch(void* const* d_in, const int* in_sizes, int n_in,
                              void* d_out, int out_size, void* d_ws,
                              size_t ws_size, hipStream_t stream)
{
    const float* x  = (const float*)d_in[0];
    const int* src  = (const int*)d_in[1];
    const int* dst  = (const int*)d_in[2];
    const float* ew = (const float*)d_in[3];
    const float* W1 = (const float*)d_in[4];
    const float* b1 = (const float*)d_in[5];
    const float* W2 = (const float*)d_in[6];
    const float* b2 = (const float*)d_in[7];
    float* out = (float*)d_out;

    // workspace layout:
    //   z1   [NN*DH*4] = 51.2 MB
    //   z2   [NN*NC*4] = 25.6 MB
    //   srcw [NE*8]    = 12.8 MB
    //   rowptr [(NN+2)*4], offs/cnt [NN*4], bsum [512*4]
    char* base = (char*)d_ws;
    float* z1   = (float*)base;                 base += (size_t)NN * DH * 4;
    float* z2   = (float*)base;                 base += (size_t)NN * NC * 4;
    int2*  srcw = (int2*)base;                  base += (size_t)NE * 8;
    int* rowptr = (int*)base;                   base += ((size_t)NN + 2) * 4;
    int* offs   = (int*)base;                   base += (size_t)NN * 4;
    int* bsum   = (int*)base;                   base += 512 * 4;
    int* cnt    = offs;                         // cnt dead after scanA

    hipMemsetAsync(cnt, 0, (size_t)NN * 4, stream);

    k_norm_gemm1<<<1024, 512, 0, stream>>>(x, W1, b1, z1);

    k_hist   <<<2048, 256, 0, stream>>>(dst, cnt);
    k_scanA  <<<NB, 256, 0, stream>>>(cnt, rowptr, bsum);
    k_scanB  <<<1, 512, 0, stream>>>(bsum);
    k_scanC  <<<NB, 256, 0, stream>>>(rowptr, bsum, offs);
    k_scatter<<<2048, 256, 0, stream>>>(src, dst, ew, offs, srcw);

    k_spmm1_gemm2   <<<2048, 256, 0, stream>>>(z1, rowptr, srcw, W2, b2, z2);
    k_spmm2_softmax <<<(NN + 3) / 4, 256, 0, stream>>>(z2, rowptr, srcw, out);
}

// Round 6
// 484.541 us; speedup vs baseline: 1.4683x; 1.0001x over previous
//
#include <hip/hip_runtime.h>
#include <math.h>

constexpr int NN = 100000;   // nodes
constexpr int NE = 1600000;  // edges
constexpr int DI = 128;      // input dim
constexpr int DH = 128;      // hidden dim
constexpr int NC = 64;       // classes
constexpr int NB = (NN + 255) / 256;   // 391 scan blocks

// bf16 pack/unpack (RNE). Internal tensors z1/z2 stored bf16 to halve
// gather traffic; error budget: ~0.4% rel -> ~1-3e-3 on softmax out,
// threshold 5.47e-3.
__device__ __forceinline__ unsigned short f2bf(float f) {
    const unsigned u = __float_as_uint(f);
    return (unsigned short)((u + 0x7FFFu + ((u >> 16) & 1u)) >> 16);
}
__device__ __forceinline__ float bf_lo(unsigned u) {   // bits 15:0
    return __uint_as_float(u << 16);
}
__device__ __forceinline__ float bf_hi(unsigned u) {   // bits 31:16
    return __uint_as_float(u & 0xFFFF0000u);
}

// ---------------------------------------------------------------------------
// Kernel 1: z1 = bf16(l2normalize(x) @ W1 + b1)
// 512 threads, 4 rows/wave/iter, quad-paired conflict-free W layout (round-5).
// ---------------------------------------------------------------------------
__global__ __launch_bounds__(512) void k_norm_gemm1(
    const float* __restrict__ x, const float* __restrict__ W1,
    const float* __restrict__ b1, unsigned short* __restrict__ z1h)
{
    __shared__ float4 sW4[64][64];   // 64 KB quad-paired
    __shared__ float sx[8][4][DI];   // 16 KB

    const int tid = threadIdx.x;
    for (int i = tid; i < 64 * 64; i += 512) {
        const int k2 = i >> 6, c = i & 63;
        const float* wp = W1 + (size_t)(2 * k2) * DH + c;
        sW4[k2][c] = make_float4(wp[0], wp[64], wp[DH], wp[DH + 64]);
    }
    __syncthreads();

    const int wave = tid >> 6, lane = tid & 63;
    const float bias0 = b1[lane];
    const float bias1 = b1[64 + lane];

    for (int base = (blockIdx.x * 8 + wave) * 4; base < NN;
         base += gridDim.x * 32) {
        #pragma unroll
        for (int r = 0; r < 4; ++r) {
            const int row = base + r;
            float a0 = 0.f, a1 = 0.f;
            if (row < NN) {
                a0 = x[(size_t)row * DI + lane];
                a1 = x[(size_t)row * DI + 64 + lane];
            }
            float ss = a0 * a0 + a1 * a1;
            #pragma unroll
            for (int off = 32; off; off >>= 1) ss += __shfl_xor(ss, off);
            const float rinv = 1.0f / fmaxf(sqrtf(ss), 1e-12f);
            sx[wave][r][lane]      = a0 * rinv;
            sx[wave][r][64 + lane] = a1 * rinv;
        }

        float acc[4][2];
        #pragma unroll
        for (int r = 0; r < 4; ++r) { acc[r][0] = bias0; acc[r][1] = bias1; }

        #pragma unroll 2
        for (int k2 = 0; k2 < 64; k2 += 2) {
            const float4 w0 = sW4[k2][lane];
            const float4 w1 = sW4[k2 + 1][lane];
            #pragma unroll
            for (int r = 0; r < 4; ++r) {
                const float4 xv = *(const float4*)(&sx[wave][r][2 * k2]);
                acc[r][0] = fmaf(xv.x, w0.x, acc[r][0]);
                acc[r][1] = fmaf(xv.x, w0.y, acc[r][1]);
                acc[r][0] = fmaf(xv.y, w0.z, acc[r][0]);
                acc[r][1] = fmaf(xv.y, w0.w, acc[r][1]);
                acc[r][0] = fmaf(xv.z, w1.x, acc[r][0]);
                acc[r][1] = fmaf(xv.z, w1.y, acc[r][1]);
                acc[r][0] = fmaf(xv.w, w1.z, acc[r][0]);
                acc[r][1] = fmaf(xv.w, w1.w, acc[r][1]);
            }
        }
        #pragma unroll
        for (int r = 0; r < 4; ++r) {
            const int row = base + r;
            if (row < NN) {
                z1h[(size_t)row * DH + lane]      = f2bf(acc[r][0]);
                z1h[(size_t)row * DH + 64 + lane] = f2bf(acc[r][1]);
            }
        }
    }
}

// ---------------------------------------------------------------------------
// CSR build: histogram -> 3-kernel exclusive scan -> (src,w) scatter
// ---------------------------------------------------------------------------
__global__ __launch_bounds__(256) void k_hist(
    const int* __restrict__ dst, int* __restrict__ cnt)
{
    for (int e = blockIdx.x * 256 + threadIdx.x; e < NE; e += gridDim.x * 256)
        atomicAdd(&cnt[dst[e]], 1);
}

__global__ __launch_bounds__(256) void k_scanA(
    const int* __restrict__ cnt, int* __restrict__ rowptr,
    int* __restrict__ bsum)
{
    __shared__ int tmp[256];
    const int t = threadIdx.x;
    const int gid = blockIdx.x * 256 + t;
    const int v = (gid < NN) ? cnt[gid] : 0;
    tmp[t] = v;
    __syncthreads();
    #pragma unroll
    for (int off = 1; off < 256; off <<= 1) {
        const int add = (t >= off) ? tmp[t - off] : 0;
        __syncthreads();
        tmp[t] += add;
        __syncthreads();
    }
    if (gid < NN) rowptr[gid] = tmp[t] - v;
    if (t == 255) bsum[blockIdx.x] = tmp[255];
}

__global__ __launch_bounds__(512) void k_scanB(int* __restrict__ bsum)
{
    __shared__ int tmp[512];
    const int t = threadIdx.x;
    const int v = (t < NB) ? bsum[t] : 0;
    tmp[t] = v;
    __syncthreads();
    #pragma unroll
    for (int off = 1; off < 512; off <<= 1) {
        const int add = (t >= off) ? tmp[t - off] : 0;
        __syncthreads();
        tmp[t] += add;
        __syncthreads();
    }
    if (t < NB) bsum[t] = tmp[t] - v;
}

__global__ __launch_bounds__(256) void k_scanC(
    int* __restrict__ rowptr, const int* __restrict__ bsum,
    int* __restrict__ offs)
{
    const int gid = blockIdx.x * 256 + threadIdx.x;
    if (gid < NN) {
        const int r = rowptr[gid] + bsum[blockIdx.x];
        rowptr[gid] = r;
        offs[gid]   = r;
    }
    if (gid == 0) rowptr[NN] = NE;
}

__global__ __launch_bounds__(256) void k_scatter(
    const int* __restrict__ src, const int* __restrict__ dst,
    const float* __restrict__ ew, int* __restrict__ offs,
    int2* __restrict__ srcw)
{
    for (int e = blockIdx.x * 256 + threadIdx.x; e < NE; e += gridDim.x * 256) {
        const int pos = atomicAdd(&offs[dst[e]], 1);
        srcw[pos] = make_int2(src[e], __float_as_int(ew[e]));
    }
}

// ---------------------------------------------------------------------------
// Fused: agg = relu(spmm(z1h)); z2 = bf16(agg @ W2 + b2)
// 512 threads (36KB LDS -> 4 blocks/CU = 32 waves/CU, was 40% occ at 256).
// Lane owns dims (2l, 2l+1): ONE uint load = 2 bf16 dims per edge.
// ---------------------------------------------------------------------------
__global__ __launch_bounds__(512) void k_spmm1_gemm2(
    const unsigned short* __restrict__ h, const int* __restrict__ rowptr,
    const int2* __restrict__ srcw, const float* __restrict__ W2,
    const float* __restrict__ b2, unsigned short* __restrict__ z2h)
{
    __shared__ float sW2[DH * NC];   // 32 KB
    __shared__ float sagg[8][DH];    // 4 KB

    const int tid = threadIdx.x;
    {
        const float4* W4 = (const float4*)W2;
        float4* s4 = (float4*)sW2;
        #pragma unroll
        for (int i = 0; i < DH * NC / 4 / 512; ++i)
            s4[tid + i * 512] = W4[tid + i * 512];
    }
    __syncthreads();

    const int wave = tid >> 6, lane = tid & 63;
    const float bias = b2[lane];
    const unsigned* hu = (const unsigned*)h;   // 64 uints per row

    for (int row = blockIdx.x * 8 + wave; row < NN; row += gridDim.x * 8) {
        const int start = rowptr[row], end = rowptr[row + 1];
        float acc0 = 0.f, acc1 = 0.f;   // dims 2*lane, 2*lane+1
        int e = start;
        for (; e + 4 <= end; e += 4) {
            const int2 s0 = srcw[e + 0], s1 = srcw[e + 1];
            const int2 s2 = srcw[e + 2], s3 = srcw[e + 3];
            const unsigned u0 = hu[(size_t)s0.x * 64 + lane];
            const unsigned u1 = hu[(size_t)s1.x * 64 + lane];
            const unsigned u2 = hu[(size_t)s2.x * 64 + lane];
            const unsigned u3 = hu[(size_t)s3.x * 64 + lane];
            const float w0 = __int_as_float(s0.y), w1 = __int_as_float(s1.y);
            const float w2 = __int_as_float(s2.y), w3 = __int_as_float(s3.y);
            acc0 = fmaf(w0, bf_lo(u0), acc0); acc1 = fmaf(w0, bf_hi(u0), acc1);
            acc0 = fmaf(w1, bf_lo(u1), acc0); acc1 = fmaf(w1, bf_hi(u1), acc1);
            acc0 = fmaf(w2, bf_lo(u2), acc0); acc1 = fmaf(w2, bf_hi(u2), acc1);
            acc0 = fmaf(w3, bf_lo(u3), acc0); acc1 = fmaf(w3, bf_hi(u3), acc1);
        }
        for (; e < end; ++e) {
            const int2 s = srcw[e];
            const unsigned u = hu[(size_t)s.x * 64 + lane];
            const float w = __int_as_float(s.y);
            acc0 = fmaf(w, bf_lo(u), acc0);
            acc1 = fmaf(w, bf_hi(u), acc1);
        }
        // ReLU into per-wave LDS (agg never hits global)
        *(float2*)&sagg[wave][2 * lane] =
            make_float2(fmaxf(acc0, 0.f), fmaxf(acc1, 0.f));

        float acc = bias;
        #pragma unroll
        for (int k = 0; k < DH; k += 4) {
            float a4[4];
            *(float4*)a4 = *(const float4*)(&sagg[wave][k]);
            acc = fmaf(a4[0], sW2[(k + 0) * NC + lane], acc);
            acc = fmaf(a4[1], sW2[(k + 1) * NC + lane], acc);
            acc = fmaf(a4[2], sW2[(k + 2) * NC + lane], acc);
            acc = fmaf(a4[3], sW2[(k + 3) * NC + lane], acc);
        }
        z2h[(size_t)row * NC + lane] = f2bf(acc);
    }
}

// ---------------------------------------------------------------------------
// Gather-SPMM D=64 (bf16 table) + fused softmax, x4 edge unroll
// ---------------------------------------------------------------------------
__global__ __launch_bounds__(256) void k_spmm2_softmax(
    const unsigned short* __restrict__ z2h, const int* __restrict__ rowptr,
    const int2* __restrict__ srcw, float* __restrict__ out)
{
    const int row = blockIdx.x * 4 + (threadIdx.x >> 6);
    if (row >= NN) return;
    const int lane = threadIdx.x & 63;
    const int start = rowptr[row], end = rowptr[row + 1];
    float acc = 0.f;
    int e = start;
    for (; e + 4 <= end; e += 4) {
        const int2 s0 = srcw[e + 0], s1 = srcw[e + 1];
        const int2 s2 = srcw[e + 2], s3 = srcw[e + 3];
        const float v0 = __uint_as_float((unsigned)z2h[(size_t)s0.x * NC + lane] << 16);
        const float v1 = __uint_as_float((unsigned)z2h[(size_t)s1.x * NC + lane] << 16);
        const float v2 = __uint_as_float((unsigned)z2h[(size_t)s2.x * NC + lane] << 16);
        const float v3 = __uint_as_float((unsigned)z2h[(size_t)s3.x * NC + lane] << 16);
        acc = fmaf(__int_as_float(s0.y), v0, acc);
        acc = fmaf(__int_as_float(s1.y), v1, acc);
        acc = fmaf(__int_as_float(s2.y), v2, acc);
        acc = fmaf(__int_as_float(s3.y), v3, acc);
    }
    for (; e < end; ++e) {
        const int2 s = srcw[e];
        const float v = __uint_as_float((unsigned)z2h[(size_t)s.x * NC + lane] << 16);
        acc = fmaf(__int_as_float(s.y), v, acc);
    }
    float m = acc;
    #pragma unroll
    for (int off = 32; off; off >>= 1) m = fmaxf(m, __shfl_xor(m, off));
    const float ex = __expf(acc - m);
    float s = ex;
    #pragma unroll
    for (int off = 32; off; off >>= 1) s += __shfl_xor(s, off);
    out[(size_t)row * NC + lane] = ex / s;
}

// ---------------------------------------------------------------------------
extern "C" void kernel_launch(void* const* d_in, const int* in_sizes, int n_in,
                              void* d_out, int out_size, void* d_ws,
                              size_t ws_size, hipStream_t stream)
{
    const float* x  = (const float*)d_in[0];
    const int* src  = (const int*)d_in[1];
    const int* dst  = (const int*)d_in[2];
    const float* ew = (const float*)d_in[3];
    const float* W1 = (const float*)d_in[4];
    const float* b1 = (const float*)d_in[5];
    const float* W2 = (const float*)d_in[6];
    const float* b2 = (const float*)d_in[7];
    float* out = (float*)d_out;

    // workspace layout:
    //   z1h  [NN*DH*2] = 25.6 MB (bf16)
    //   z2h  [NN*NC*2] = 12.8 MB (bf16)
    //   srcw [NE*8]    = 12.8 MB
    //   rowptr [(NN+2)*4], offs/cnt [NN*4], bsum [512*4]
    char* base = (char*)d_ws;
    unsigned short* z1h = (unsigned short*)base;  base += (size_t)NN * DH * 2;
    unsigned short* z2h = (unsigned short*)base;  base += (size_t)NN * NC * 2;
    int2*  srcw = (int2*)base;                    base += (size_t)NE * 8;
    int* rowptr = (int*)base;                     base += ((size_t)NN + 2) * 4;
    int* offs   = (int*)base;                     base += (size_t)NN * 4;
    int* bsum   = (int*)base;                     base += 512 * 4;
    int* cnt    = offs;                           // cnt dead after scanA

    hipMemsetAsync(cnt, 0, (size_t)NN * 4, stream);

    k_norm_gemm1<<<1024, 512, 0, stream>>>(x, W1, b1, z1h);

    k_hist   <<<2048, 256, 0, stream>>>(dst, cnt);
    k_scanA  <<<NB, 256, 0, stream>>>(cnt, rowptr, bsum);
    k_scanB  <<<1, 512, 0, stream>>>(bsum);
    k_scanC  <<<NB, 256, 0, stream>>>(rowptr, bsum, offs);
    k_scatter<<<2048, 256, 0, stream>>>(src, dst, ew, offs, srcw);

    k_spmm1_gemm2   <<<2048, 512, 0, stream>>>(z1h, rowptr, srcw, W2, b2, z2h);
    k_spmm2_softmax <<<(NN + 3) / 4, 256, 0, stream>>>(z2h, rowptr, srcw, out);
}